// Round 2
// baseline (31080.734 us; speedup 1.0000x reference)
//
#include <hip/hip_runtime.h>
#include <math.h>

#define VOCN 32000
#define HN 512
#define TN 256
#define BN 64
#define MAXLENN 32
#define SOSW 1

// ---------------- workspace layout (float/int32 units) ----------------
#define WS_BAR      0                       // 512 barrier slots * 16 ints (64B apart)
#define WS_H        8192                    // h buffers [2 parity][2 layer][64][512]
#define WS_WORD     (WS_H + 131072)         // 64 ints
#define WS_A        (WS_WORD + 64)          // a[64][256]
#define WS_APPLIED  (WS_A + 16384)          // [64][512]
#define WS_COMB     (WS_APPLIED + 32768)    // [64][512]
#define WS_PVAL     (WS_COMB + 32768)       // [256][64]
#define WS_PIDX     (WS_PVAL + 16384)       // [256][64] int
#define WS_GRUOUT   (WS_PIDX + 16384)       // [256][64][512]
#define WS_ZERO_BYTES ((WS_H + 131072) * 4) // zero barriers + h state

__device__ __forceinline__ float4 ld4(const float* p) { return *(const float4*)p; }
__device__ __forceinline__ float dot4(float4 a, float4 b, float acc) {
  acc = fmaf(a.x, b.x, acc); acc = fmaf(a.y, b.y, acc);
  acc = fmaf(a.z, b.z, acc); acc = fmaf(a.w, b.w, acc); return acc;
}
__device__ __forceinline__ float4 relu4(float4 v) {
  v.x = fmaxf(v.x, 0.f); v.y = fmaxf(v.y, 0.f);
  v.z = fmaxf(v.z, 0.f); v.w = fmaxf(v.w, 0.f); return v;
}
__device__ __forceinline__ float sigmoidf_(float x) { return 1.f / (1.f + expf(-x)); }

// one-shot slot barrier: slots pre-zeroed by hipMemsetAsync; each barrier uses a fresh slot.
// Works under a plain launch because 256 blocks x (4 waves, 34KB LDS) are all
// simultaneously resident on 256 CUs (1 block/CU).
__device__ __forceinline__ void grid_barrier(int* bar, int idx) {
  __syncthreads();
  if (threadIdx.x == 0) {
    __threadfence();  // release: make this block's stores visible device-wide
    int* slot = bar + idx * 16;
    __hip_atomic_fetch_add(slot, 1, __ATOMIC_RELAXED, __HIP_MEMORY_SCOPE_AGENT);
    while (__hip_atomic_load(slot, __ATOMIC_RELAXED, __HIP_MEMORY_SCOPE_AGENT) < 256) {
      __builtin_amdgcn_s_sleep(1);
    }
    __threadfence();  // acquire
  }
  __syncthreads();
}

// GRU layer phase. 128 blocks participate: rb in [0,128); bg=rb>>6 (batch half), jg=rb&63.
// Each thread computes all 3 gates (full K=512 dots) for one (b, j) and combines locally.
// x/h staged in LDS as XOR-swizzled float4 (conflict-free reads), reg-prefetched per K-chunk.
__device__ __forceinline__ void gru_phase(
    const float* __restrict__ x_base, const int* __restrict__ tok,
    const float* __restrict__ h_rows,
    const float* __restrict__ Wih, const float* __restrict__ Whh,
    const float* __restrict__ bih, const float* __restrict__ bhh,
    float* __restrict__ h_out, float* __restrict__ aux_out,
    int rb, float* lds)
{
  const int tid = threadIdx.x;
  const int bg = rb >> 6;
  const int jg = rb & 63;
  float4* x4l = (float4*)lds;          // 1024 quads (16KB)
  float4* h4l = ((float4*)lds) + 1024; // 1024 quads (16KB)

  const float* xp[4]; const float* hp[4]; int loff[4];
#pragma unroll
  for (int i = 0; i < 4; ++i) {
    int tau = tid + (i << 8);
    int b = tau >> 5;        // [0,32)
    int kq = tau & 31;
    int gb = bg * 32 + b;
    const float* xr = tok ? (x_base + (size_t)tok[gb] * HN) : (x_base + (size_t)gb * HN);
    xp[i] = xr + (kq << 2);
    hp[i] = h_rows + (size_t)gb * HN + (kq << 2);
    loff[i] = (b << 5) + (kq ^ (b & 7));
  }
  const bool dorelu = (tok != nullptr);
  float4 pxv[4], phv[4];
#pragma unroll
  for (int i = 0; i < 4; ++i) { pxv[i] = ld4(xp[i]); phv[i] = ld4(hp[i]); }

  const int bl = tid & 31;
  const int jl = tid >> 5;          // [0,8)
  const int j = (jg << 3) + jl;     // [0,512)
  const float* wi0 = Wih + (size_t)j * HN;
  const float* wi1 = Wih + (size_t)(512 + j) * HN;
  const float* wi2 = Wih + (size_t)(1024 + j) * HN;
  const float* wh0 = Whh + (size_t)j * HN;
  const float* wh1 = Whh + (size_t)(512 + j) * HN;
  const float* wh2 = Whh + (size_t)(1024 + j) * HN;
  float ax0 = 0.f, ax1 = 0.f, ax2 = 0.f, ah0 = 0.f, ah1 = 0.f, ah2 = 0.f;
  const int rdbase = bl << 5;
  const int rdx = bl & 7;

#pragma unroll 1
  for (int ch = 0; ch < 4; ++ch) {
    __syncthreads();
#pragma unroll
    for (int i = 0; i < 4; ++i) {
      x4l[loff[i]] = dorelu ? relu4(pxv[i]) : pxv[i];
      h4l[loff[i]] = phv[i];
    }
    __syncthreads();
    if (ch < 3) {
#pragma unroll
      for (int i = 0; i < 4; ++i) {
        pxv[i] = ld4(xp[i] + (ch + 1) * 128);
        phv[i] = ld4(hp[i] + (ch + 1) * 128);
      }
    }
    const int k0 = ch << 7;
#pragma unroll 4
    for (int kq = 0; kq < 32; ++kq) {
      float4 xv = x4l[rdbase + (kq ^ rdx)];
      float4 hv = h4l[rdbase + (kq ^ rdx)];
      const int kk = k0 + (kq << 2);
      ax0 = dot4(xv, ld4(wi0 + kk), ax0);
      ah0 = dot4(hv, ld4(wh0 + kk), ah0);
      ax1 = dot4(xv, ld4(wi1 + kk), ax1);
      ah1 = dot4(hv, ld4(wh1 + kk), ah1);
      ax2 = dot4(xv, ld4(wi2 + kk), ax2);
      ah2 = dot4(hv, ld4(wh2 + kk), ah2);
    }
  }
  const int gb = bg * 32 + bl;
  const float hold = h_rows[(size_t)gb * HN + j];
  const float r = sigmoidf_(ax0 + bih[j] + ah0 + bhh[j]);
  const float z = sigmoidf_(ax1 + bih[512 + j] + ah1 + bhh[512 + j]);
  const float n = tanhf(ax2 + bih[1024 + j] + r * (ah2 + bhh[1024 + j]));
  const float hv = (1.f - z) * n + z * hold;
  h_out[(size_t)gb * HN + j] = hv;
  if (aux_out) aux_out[(size_t)gb * HN + j] = hv;
}

// D1: a[b, tau=bid] = relu(cat(e, sv) @ attn_W[tau] + attn_b[tau]); sv is the raw reshape.
__device__ __forceinline__ void d1_attn(
    const float* __restrict__ emb_dec, const int* __restrict__ word_buf, int s,
    const float* __restrict__ hflat, const float* __restrict__ attn_W,
    const float* __restrict__ attn_b, float* __restrict__ a_buf, int bid, float* lds)
{
  const int tid = threadIdx.x;
  const int b = tid & 63, q = tid >> 6;
  const int wb = (s == 0) ? SOSW : word_buf[b];
  const float* er = emb_dec + (size_t)wb * HN;
  const float* hr = hflat + b * 1024;
  const float* wr = attn_W + (size_t)bid * 1536;
  float acc = 0.f;
  const int kbeg = q * 384;
  for (int k = kbeg; k < kbeg + 384; k += 4) {
    float4 xv = (k < 512) ? relu4(ld4(er + k)) : ld4(hr + (k - 512));
    acc = dot4(xv, ld4(wr + k), acc);
  }
  lds[(b << 2) + q] = acc;
  __syncthreads();
  if (tid < 64) {
    float v = lds[tid * 4] + lds[tid * 4 + 1] + lds[tid * 4 + 2] + lds[tid * 4 + 3];
    v += attn_b[bid];
    a_buf[tid * 256 + bid] = fmaxf(v, 0.f);
  }
}

// D2: applied[b,h] = sum_t a[b,t] * gru_out[t,b,h]; block = (b, h-chunk of 128)
__device__ __forceinline__ void d2_applied(const float* __restrict__ a_buf,
    const float* __restrict__ gru_out, float* __restrict__ applied, int bid, float* lds)
{
  const int tid = threadIdx.x;
  const int b = bid & 63, hc = bid >> 6;
  const int hl = tid & 127, th = tid >> 7;
  const int hh = (hc << 7) + hl;
  const float* gp = gru_out + (size_t)b * HN + hh;
  const float* ap = a_buf + b * 256;
  float acc = 0.f;
  const int t0 = th << 7;
#pragma unroll 4
  for (int t = t0; t < t0 + 128; ++t)
    acc = fmaf(ap[t], gp[(size_t)t * (BN * HN)], acc);
  lds[tid] = acc;
  __syncthreads();
  if (tid < 128) applied[(size_t)b * HN + (hc << 7) + tid] = lds[tid] + lds[tid + 128];
}

// D3: comb[b,col] = relu(cat(e, applied) @ comb_W[col] + comb_b[col]); block owns 2 cols
__device__ __forceinline__ void d3_comb(const float* __restrict__ emb_dec,
    const int* __restrict__ word_buf, int s, const float* __restrict__ applied,
    const float* __restrict__ comb_W, const float* __restrict__ comb_b,
    float* __restrict__ comb, int bid, float* lds)
{
  const int tid = threadIdx.x;
  const int b = tid & 63, q = tid >> 6;
  const int wb = (s == 0) ? SOSW : word_buf[b];
  const float* er = emb_dec + (size_t)wb * HN;
  const float* apr = applied + (size_t)b * HN;
#pragma unroll
  for (int cc = 0; cc < 2; ++cc) {
    const int col = (bid << 1) + cc;
    const float* wr = comb_W + (size_t)col * 1024;
    float acc = 0.f;
    const int kbeg = q << 8;
    for (int k = kbeg; k < kbeg + 256; k += 4) {
      float4 xv = (k < 512) ? relu4(ld4(er + k)) : ld4(apr + (k - 512));
      acc = dot4(xv, ld4(wr + k), acc);
    }
    lds[cc * 256 + (b << 2) + q] = acc;
  }
  __syncthreads();
  if (tid < 128) {
    const int cc = tid >> 6, b2 = tid & 63;
    const int col = (bid << 1) + cc;
    float v = lds[cc * 256 + b2 * 4] + lds[cc * 256 + b2 * 4 + 1] +
              lds[cc * 256 + b2 * 4 + 2] + lds[cc * 256 + b2 * 4 + 3];
    v += comb_b[col];
    comb[(size_t)b2 * HN + col] = fmaxf(v, 0.f);
  }
}

// D6: per-block partial argmax over its 125 adv_W columns for all 64 rows.
// top staged in LDS (swizzled), 8 cols share each top quad load.
__device__ __forceinline__ void d6_values(const float* __restrict__ top,
    const float* __restrict__ adv_W, float* __restrict__ pval, int* __restrict__ pidx,
    int bid, float* lds)
{
  const int tid = threadIdx.x;
  const int c0 = bid * 125;
  float4* tl = (float4*)lds;           // 2048 quads (32KB)
  float* sval = lds + 8192;
  int* sidx = (int*)(lds + 8192 + 256);

  int voff[8], loff[8];
#pragma unroll
  for (int i = 0; i < 8; ++i) {
    int tau = tid + (i << 8);
    int b = tau >> 5, kq = tau & 31;
    voff[i] = b * HN + (kq << 2);
    loff[i] = (b << 5) + (kq ^ (b & 7));
  }
  float4 pv[8];
#pragma unroll
  for (int i = 0; i < 8; ++i) pv[i] = ld4(top + voff[i]);

  const int bl = tid & 63;
  const int half = tid >> 6;
  const int rdbase = bl << 5;
  const int rdx = bl & 7;

  float acc[32];
#pragma unroll
  for (int i = 0; i < 32; ++i) acc[i] = 0.f;

#pragma unroll 1
  for (int ch = 0; ch < 4; ++ch) {
    __syncthreads();
#pragma unroll
    for (int i = 0; i < 8; ++i) tl[loff[i]] = pv[i];
    __syncthreads();
    if (ch < 3) {
#pragma unroll
      for (int i = 0; i < 8; ++i) pv[i] = ld4(top + voff[i] + (ch + 1) * 128);
    }
    const int kk0 = ch << 7;
#pragma unroll
    for (int g = 0; g < 4; ++g) {
      const float* ar[8];
#pragma unroll
      for (int jj = 0; jj < 8; ++jj) {
        int c = c0 + (half << 5) + (g << 3) + jj;
        if (c > VOCN - 1) c = VOCN - 1;
        ar[jj] = adv_W + (size_t)c * HN + kk0;
      }
#pragma unroll 4
      for (int kq = 0; kq < 32; ++kq) {
        float4 tv = tl[rdbase + (kq ^ rdx)];
        const int kk = kq << 2;
        acc[(g << 3) + 0] = dot4(tv, ld4(ar[0] + kk), acc[(g << 3) + 0]);
        acc[(g << 3) + 1] = dot4(tv, ld4(ar[1] + kk), acc[(g << 3) + 1]);
        acc[(g << 3) + 2] = dot4(tv, ld4(ar[2] + kk), acc[(g << 3) + 2]);
        acc[(g << 3) + 3] = dot4(tv, ld4(ar[3] + kk), acc[(g << 3) + 3]);
        acc[(g << 3) + 4] = dot4(tv, ld4(ar[4] + kk), acc[(g << 3) + 4]);
        acc[(g << 3) + 5] = dot4(tv, ld4(ar[5] + kk), acc[(g << 3) + 5]);
        acc[(g << 3) + 6] = dot4(tv, ld4(ar[6] + kk), acc[(g << 3) + 6]);
        acc[(g << 3) + 7] = dot4(tv, ld4(ar[7] + kk), acc[(g << 3) + 7]);
      }
    }
  }
  float bv = -3.4e38f; int bi = 2147483647;
#pragma unroll
  for (int i = 0; i < 32; ++i) {
    const int cl = (half << 5) + i;
    if (cl < 125) {
      float v = acc[i];
      if (v > bv) { bv = v; bi = c0 + cl; }   // ascending order -> first-max on ties
    }
  }
  sval[(bl << 2) + half] = bv;
  sidx[(bl << 2) + half] = bi;
  __syncthreads();
  if (tid < 64) {
    float v = sval[tid << 2]; int ii = sidx[tid << 2];
#pragma unroll
    for (int h2 = 1; h2 < 4; ++h2) {
      float v2 = sval[(tid << 2) + h2]; int i2 = sidx[(tid << 2) + h2];
      if (v2 > v || (v2 == v && i2 < ii)) { v = v2; ii = i2; }
    }
    pval[bid * 64 + tid] = v;
    pidx[bid * 64 + tid] = ii;
  }
}

// D7 (block 0): avg dot + global argmax reduce -> q, next word
__device__ __forceinline__ void d7_reduce(const float* __restrict__ top,
    const float* __restrict__ avg_W, const float* __restrict__ pval,
    const int* __restrict__ pidx, float* __restrict__ qs_out,
    int* __restrict__ word_buf, float* lds)
{
  const int tid = threadIdx.x;
  const int b = tid & 63, q = tid >> 6;
  const float* tr = top + (size_t)b * HN;
  float p = 0.f;
  const int kbeg = q << 7;
  for (int k = kbeg; k < kbeg + 128; k += 4)
    p = dot4(ld4(tr + k), ld4(avg_W + k), p);
  float* av = lds;            // [64][4]
  float* avl = lds + 256;     // [64]
  float* rv = lds + 320;      // [64][4]
  int* ri = (int*)(lds + 576);// [64][4]
  av[(b << 2) + q] = p;
  __syncthreads();
  if (tid < 64)
    avl[tid] = av[tid * 4] + av[tid * 4 + 1] + av[tid * 4 + 2] + av[tid * 4 + 3];
  float bv = -3.4e38f; int bi = 2147483647;
#pragma unroll 4
  for (int pp = (q << 6); pp < (q << 6) + 64; ++pp) {
    float v = pval[pp * 64 + b]; int ii = pidx[pp * 64 + b];
    if (v > bv || (v == bv && ii < bi)) { bv = v; bi = ii; }
  }
  rv[(b << 2) + q] = bv;
  ri[(b << 2) + q] = bi;
  __syncthreads();
  if (tid < 64) {
    float v = rv[tid << 2]; int ii = ri[tid << 2];
#pragma unroll
    for (int k = 1; k < 4; ++k) {
      float v2 = rv[(tid << 2) + k]; int i2 = ri[(tid << 2) + k];
      if (v2 > v || (v2 == v && i2 < ii)) { v = v2; ii = i2; }
    }
    qs_out[tid] = v + avl[tid];
    word_buf[tid] = ii;
  }
}

__global__ void __launch_bounds__(256)
seq2seq_kernel(const int* __restrict__ input, const float* __restrict__ emb_enc,
               const float* __restrict__ emb_dec,
               const float* __restrict__ enc_Wih, const float* __restrict__ enc_Whh,
               const float* __restrict__ enc_bih, const float* __restrict__ enc_bhh,
               const float* __restrict__ dec_Wih, const float* __restrict__ dec_Whh,
               const float* __restrict__ dec_bih, const float* __restrict__ dec_bhh,
               const float* __restrict__ attn_W, const float* __restrict__ attn_b,
               const float* __restrict__ comb_W, const float* __restrict__ comb_b,
               const float* __restrict__ avg_W, const float* __restrict__ adv_W,
               float* __restrict__ out, float* __restrict__ ws)
{
  __shared__ float lds[8704];   // 34KB: max(gru 32KB, d6 32KB+1KB reduce)
  const int bid = blockIdx.x;
  int* bar = (int*)ws;
  float* hbuf = ws + WS_H;                    // [parity][L][B][H], parity stride 65536
  int* word_buf = (int*)(ws + WS_WORD);
  float* a_buf = ws + WS_A;
  float* applied = ws + WS_APPLIED;
  float* comb = ws + WS_COMB;
  float* pval = ws + WS_PVAL;
  int* pidx = (int*)(ws + WS_PIDX);
  float* gru_out = ws + WS_GRUOUT;
  int barIdx = 0;

  // ---------------- encoder: software-pipelined, 1 barrier/step ----------------
#pragma unroll 1
  for (int p = 0; p <= 256; ++p) {
    if (bid < 128) {
      if (p < 256) {          // layer 0 of step p:  h0^p -> h0^{p+1}
        const int t = p;
        gru_phase(emb_enc, input + t * BN,
                  hbuf + (size_t)(t & 1) * 65536,               // h0^t
                  enc_Wih, enc_Whh, enc_bih, enc_bhh,
                  hbuf + (size_t)((t + 1) & 1) * 65536,         // h0^{t+1}
                  nullptr, bid, lds);
      }
    } else {
      if (p >= 1) {           // layer 1 of step p-1 (consumes h0^{p} from prev phase)
        const int t = p - 1;
        gru_phase(hbuf + (size_t)((t + 1) & 1) * 65536, nullptr, // x = h0^{t+1}
                  hbuf + (size_t)(t & 1) * 65536 + 32768,        // h1^t
                  enc_Wih + 786432, enc_Whh + 786432,
                  enc_bih + 1536, enc_bhh + 1536,
                  hbuf + (size_t)((t + 1) & 1) * 65536 + 32768,  // h1^{t+1}
                  gru_out + (size_t)t * (BN * HN), bid - 128, lds);
      }
    }
    grid_barrier(bar, barIdx++);
  }

  // ---------------- decoder: 32 steps x 7 phases ----------------
#pragma unroll 1
  for (int s = 0; s < 32; ++s) {
    const float* hflat = hbuf + (size_t)(s & 1) * 65536;
    float* hnew = hbuf + (size_t)((s + 1) & 1) * 65536;

    d1_attn(emb_dec, word_buf, s, hflat, attn_W, attn_b, a_buf, bid, lds);
    grid_barrier(bar, barIdx++);

    d2_applied(a_buf, gru_out, applied, bid, lds);
    grid_barrier(bar, barIdx++);

    d3_comb(emb_dec, word_buf, s, applied, comb_W, comb_b, comb, bid, lds);
    grid_barrier(bar, barIdx++);

    if (bid < 128)
      gru_phase(comb, nullptr, hflat, dec_Wih, dec_Whh, dec_bih, dec_bhh,
                hnew, nullptr, bid, lds);
    grid_barrier(bar, barIdx++);

    if (bid < 128)
      gru_phase(hnew, nullptr, hflat + 32768,
                dec_Wih + 786432, dec_Whh + 786432, dec_bih + 1536, dec_bhh + 1536,
                hnew + 32768, out + (size_t)s * (BN * HN), bid, lds);
    grid_barrier(bar, barIdx++);

    d6_values(hnew + 32768, adv_W, pval, pidx, bid, lds);
    grid_barrier(bar, barIdx++);

    if (bid == 0)
      d7_reduce(hnew + 32768, avg_W, pval, pidx,
                out + (size_t)MAXLENN * BN * HN + s * BN, word_buf, lds);
    grid_barrier(bar, barIdx++);
  }
}

extern "C" void kernel_launch(void* const* d_in, const int* in_sizes, int n_in,
                              void* d_out, int out_size, void* d_ws, size_t ws_size,
                              hipStream_t stream) {
  (void)in_sizes; (void)n_in; (void)out_size; (void)ws_size;
  const int* input      = (const int*)d_in[0];
  const float* emb_enc  = (const float*)d_in[1];
  const float* emb_dec  = (const float*)d_in[2];
  const float* enc_Wih  = (const float*)d_in[3];
  const float* enc_Whh  = (const float*)d_in[4];
  const float* enc_bih  = (const float*)d_in[5];
  const float* enc_bhh  = (const float*)d_in[6];
  const float* dec_Wih  = (const float*)d_in[7];
  const float* dec_Whh  = (const float*)d_in[8];
  const float* dec_bih  = (const float*)d_in[9];
  const float* dec_bhh  = (const float*)d_in[10];
  const float* attn_W   = (const float*)d_in[11];
  const float* attn_b   = (const float*)d_in[12];
  const float* comb_W   = (const float*)d_in[13];
  const float* comb_b   = (const float*)d_in[14];
  const float* avg_W    = (const float*)d_in[15];
  const float* adv_W    = (const float*)d_in[16];
  float* out = (float*)d_out;
  float* ws  = (float*)d_ws;

  hipMemsetAsync(d_ws, 0, WS_ZERO_BYTES, stream);  // barrier slots + zero h0

  // Plain persistent launch: 256 blocks on 256 CUs, 1 block/CU (4 waves, 34KB LDS)
  // -> all blocks co-resident, spin barrier is safe. Avoids hipLaunchCooperativeKernel,
  // which silently failed in round 1 (output identical to the empty stub) and which
  // is fragile under hipGraph capture.
  seq2seq_kernel<<<dim3(256), dim3(256), 0, stream>>>(
      input, emb_enc, emb_dec, enc_Wih, enc_Whh, enc_bih, enc_bhh,
      dec_Wih, dec_Whh, dec_bih, dec_bhh, attn_W, attn_b,
      comb_W, comb_b, avg_W, adv_W, out, ws);
}

// Round 3
// 26676.175 us; speedup vs baseline: 1.1651x; 1.1651x over previous
//
#include <hip/hip_runtime.h>
#include <math.h>

#define VOCN 32000
#define HN 512
#define TN 256
#define BN 64
#define MAXLENN 32
#define SOSW 1

// ---------------- workspace layout (float/int32 units) ----------------
// Barrier: per-block private flag lines (monotone generation) + 8 replicated
// release lines. No RMW, no shared arrival line.
#define WS_FLAG     0                       // 256 blocks * 32 ints (128B line each)
#define WS_REL      8192                    // 8 release lines * 16 ints (+pad to 256)
#define WS_H        8448                    // h buffers [2 parity][2 layer][64][512]
#define WS_WORD     (WS_H + 131072)         // 64 ints
#define WS_A        (WS_WORD + 64)          // a[64][256]
#define WS_APPLIED  (WS_A + 16384)          // [64][512]
#define WS_COMB     (WS_APPLIED + 32768)    // [64][512]
#define WS_PVAL     (WS_COMB + 32768)       // [256][64]
#define WS_PIDX     (WS_PVAL + 16384)       // [256][64] int
#define WS_GRUOUT   (WS_PIDX + 16384)       // [256][64][512]
#define WS_ZERO_BYTES ((WS_H + 131072) * 4) // zero flags + rel + h state

__device__ __forceinline__ float4 ld4(const float* p) { return *(const float4*)p; }
__device__ __forceinline__ float dot4(float4 a, float4 b, float acc) {
  acc = fmaf(a.x, b.x, acc); acc = fmaf(a.y, b.y, acc);
  acc = fmaf(a.z, b.z, acc); acc = fmaf(a.w, b.w, acc); return acc;
}
__device__ __forceinline__ float4 relu4(float4 v) {
  v.x = fmaxf(v.x, 0.f); v.y = fmaxf(v.y, 0.f);
  v.z = fmaxf(v.z, 0.f); v.w = fmaxf(v.w, 0.f); return v;
}
__device__ __forceinline__ float sigmoidf_(float x) { return 1.f / (1.f + expf(-x)); }

// Contention-free grid barrier, monotone generation (gen starts at 1).
//  - every block stores gen to its OWN 128B-strided flag word (parallel, no RMW)
//  - block 0: 256 threads gather all flags, __syncthreads_and, then publish gen
//    to 8 replicated release lines
//  - other blocks: thread 0 polls its release line (<=32 pollers/line)
__device__ __forceinline__ void grid_barrier(int* wsi, int gen) {
  __syncthreads();
  const int bid = blockIdx.x;
  const int tid = threadIdx.x;
  if (tid == 0) {
    __threadfence();  // release: this block's phase stores visible device-wide
    __hip_atomic_store(wsi + WS_FLAG + bid * 32, gen,
                       __ATOMIC_RELAXED, __HIP_MEMORY_SCOPE_AGENT);
  }
  if (bid == 0) {
    int* fp = wsi + WS_FLAG + tid * 32;
    for (;;) {
      int v = __hip_atomic_load(fp, __ATOMIC_RELAXED, __HIP_MEMORY_SCOPE_AGENT);
      if (__syncthreads_and(v >= gen)) break;
      __builtin_amdgcn_s_sleep(2);
    }
    if (tid < 8) {
      __threadfence();  // order rel store after observed flags
      __hip_atomic_store(wsi + WS_REL + tid * 16, gen,
                         __ATOMIC_RELAXED, __HIP_MEMORY_SCOPE_AGENT);
    }
    __threadfence();    // acquire for block 0's own downstream reads
    __syncthreads();
  } else {
    if (tid == 0) {
      int* rp = wsi + WS_REL + (bid & 7) * 16;
      while (__hip_atomic_load(rp, __ATOMIC_RELAXED, __HIP_MEMORY_SCOPE_AGENT) < gen)
        __builtin_amdgcn_s_sleep(2);
      __threadfence();  // acquire
    }
    __syncthreads();
  }
}

// GRU layer phase. 128 blocks participate: rb in [0,128); bg=rb>>6 (batch half), jg=rb&63.
// Each thread computes all 3 gates (full K=512 dots) for one (b, j) and combines locally.
// x/h staged in LDS as XOR-swizzled float4 (conflict-free reads), reg-prefetched per K-chunk.
__device__ __forceinline__ void gru_phase(
    const float* __restrict__ x_base, const int* __restrict__ tok,
    const float* __restrict__ h_rows,
    const float* __restrict__ Wih, const float* __restrict__ Whh,
    const float* __restrict__ bih, const float* __restrict__ bhh,
    float* __restrict__ h_out, float* __restrict__ aux_out,
    int rb, float* lds)
{
  const int tid = threadIdx.x;
  const int bg = rb >> 6;
  const int jg = rb & 63;
  float4* x4l = (float4*)lds;          // 1024 quads (16KB)
  float4* h4l = ((float4*)lds) + 1024; // 1024 quads (16KB)

  const float* xp[4]; const float* hp[4]; int loff[4];
#pragma unroll
  for (int i = 0; i < 4; ++i) {
    int tau = tid + (i << 8);
    int b = tau >> 5;        // [0,32)
    int kq = tau & 31;
    int gb = bg * 32 + b;
    const float* xr = tok ? (x_base + (size_t)tok[gb] * HN) : (x_base + (size_t)gb * HN);
    xp[i] = xr + (kq << 2);
    hp[i] = h_rows + (size_t)gb * HN + (kq << 2);
    loff[i] = (b << 5) + (kq ^ (b & 7));
  }
  const bool dorelu = (tok != nullptr);
  float4 pxv[4], phv[4];
#pragma unroll
  for (int i = 0; i < 4; ++i) { pxv[i] = ld4(xp[i]); phv[i] = ld4(hp[i]); }

  const int bl = tid & 31;
  const int jl = tid >> 5;          // [0,8)
  const int j = (jg << 3) + jl;     // [0,512)
  const float* wi0 = Wih + (size_t)j * HN;
  const float* wi1 = Wih + (size_t)(512 + j) * HN;
  const float* wi2 = Wih + (size_t)(1024 + j) * HN;
  const float* wh0 = Whh + (size_t)j * HN;
  const float* wh1 = Whh + (size_t)(512 + j) * HN;
  const float* wh2 = Whh + (size_t)(1024 + j) * HN;
  float ax0 = 0.f, ax1 = 0.f, ax2 = 0.f, ah0 = 0.f, ah1 = 0.f, ah2 = 0.f;
  const int rdbase = bl << 5;
  const int rdx = bl & 7;

#pragma unroll 1
  for (int ch = 0; ch < 4; ++ch) {
    __syncthreads();
#pragma unroll
    for (int i = 0; i < 4; ++i) {
      x4l[loff[i]] = dorelu ? relu4(pxv[i]) : pxv[i];
      h4l[loff[i]] = phv[i];
    }
    __syncthreads();
    if (ch < 3) {
#pragma unroll
      for (int i = 0; i < 4; ++i) {
        pxv[i] = ld4(xp[i] + (ch + 1) * 128);
        phv[i] = ld4(hp[i] + (ch + 1) * 128);
      }
    }
    const int k0 = ch << 7;
#pragma unroll 4
    for (int kq = 0; kq < 32; ++kq) {
      float4 xv = x4l[rdbase + (kq ^ rdx)];
      float4 hv = h4l[rdbase + (kq ^ rdx)];
      const int kk = k0 + (kq << 2);
      ax0 = dot4(xv, ld4(wi0 + kk), ax0);
      ah0 = dot4(hv, ld4(wh0 + kk), ah0);
      ax1 = dot4(xv, ld4(wi1 + kk), ax1);
      ah1 = dot4(hv, ld4(wh1 + kk), ah1);
      ax2 = dot4(xv, ld4(wi2 + kk), ax2);
      ah2 = dot4(hv, ld4(wh2 + kk), ah2);
    }
  }
  const int gb = bg * 32 + bl;
  const float hold = h_rows[(size_t)gb * HN + j];
  const float r = sigmoidf_(ax0 + bih[j] + ah0 + bhh[j]);
  const float z = sigmoidf_(ax1 + bih[512 + j] + ah1 + bhh[512 + j]);
  const float n = tanhf(ax2 + bih[1024 + j] + r * (ah2 + bhh[1024 + j]));
  const float hv = (1.f - z) * n + z * hold;
  h_out[(size_t)gb * HN + j] = hv;
  if (aux_out) aux_out[(size_t)gb * HN + j] = hv;
}

// D1: a[b, tau=bid] = relu(cat(e, sv) @ attn_W[tau] + attn_b[tau]); sv is the raw reshape.
__device__ __forceinline__ void d1_attn(
    const float* __restrict__ emb_dec, const int* __restrict__ word_buf, int s,
    const float* __restrict__ hflat, const float* __restrict__ attn_W,
    const float* __restrict__ attn_b, float* __restrict__ a_buf, int bid, float* lds)
{
  const int tid = threadIdx.x;
  const int b = tid & 63, q = tid >> 6;
  const int wb = (s == 0) ? SOSW : word_buf[b];
  const float* er = emb_dec + (size_t)wb * HN;
  const float* hr = hflat + b * 1024;
  const float* wr = attn_W + (size_t)bid * 1536;
  float acc = 0.f;
  const int kbeg = q * 384;
  for (int k = kbeg; k < kbeg + 384; k += 4) {
    float4 xv = (k < 512) ? relu4(ld4(er + k)) : ld4(hr + (k - 512));
    acc = dot4(xv, ld4(wr + k), acc);
  }
  lds[(b << 2) + q] = acc;
  __syncthreads();
  if (tid < 64) {
    float v = lds[tid * 4] + lds[tid * 4 + 1] + lds[tid * 4 + 2] + lds[tid * 4 + 3];
    v += attn_b[bid];
    a_buf[tid * 256 + bid] = fmaxf(v, 0.f);
  }
}

// D2: applied[b,h] = sum_t a[b,t] * gru_out[t,b,h]; block = (b, h-chunk of 128)
__device__ __forceinline__ void d2_applied(const float* __restrict__ a_buf,
    const float* __restrict__ gru_out, float* __restrict__ applied, int bid, float* lds)
{
  const int tid = threadIdx.x;
  const int b = bid & 63, hc = bid >> 6;
  const int hl = tid & 127, th = tid >> 7;
  const int hh = (hc << 7) + hl;
  const float* gp = gru_out + (size_t)b * HN + hh;
  const float* ap = a_buf + b * 256;
  float acc = 0.f;
  const int t0 = th << 7;
#pragma unroll 4
  for (int t = t0; t < t0 + 128; ++t)
    acc = fmaf(ap[t], gp[(size_t)t * (BN * HN)], acc);
  lds[tid] = acc;
  __syncthreads();
  if (tid < 128) applied[(size_t)b * HN + (hc << 7) + tid] = lds[tid] + lds[tid + 128];
}

// D3: comb[b,col] = relu(cat(e, applied) @ comb_W[col] + comb_b[col]); block owns 2 cols
__device__ __forceinline__ void d3_comb(const float* __restrict__ emb_dec,
    const int* __restrict__ word_buf, int s, const float* __restrict__ applied,
    const float* __restrict__ comb_W, const float* __restrict__ comb_b,
    float* __restrict__ comb, int bid, float* lds)
{
  const int tid = threadIdx.x;
  const int b = tid & 63, q = tid >> 6;
  const int wb = (s == 0) ? SOSW : word_buf[b];
  const float* er = emb_dec + (size_t)wb * HN;
  const float* apr = applied + (size_t)b * HN;
#pragma unroll
  for (int cc = 0; cc < 2; ++cc) {
    const int col = (bid << 1) + cc;
    const float* wr = comb_W + (size_t)col * 1024;
    float acc = 0.f;
    const int kbeg = q << 8;
    for (int k = kbeg; k < kbeg + 256; k += 4) {
      float4 xv = (k < 512) ? relu4(ld4(er + k)) : ld4(apr + (k - 512));
      acc = dot4(xv, ld4(wr + k), acc);
    }
    lds[cc * 256 + (b << 2) + q] = acc;
  }
  __syncthreads();
  if (tid < 128) {
    const int cc = tid >> 6, b2 = tid & 63;
    const int col = (bid << 1) + cc;
    float v = lds[cc * 256 + b2 * 4] + lds[cc * 256 + b2 * 4 + 1] +
              lds[cc * 256 + b2 * 4 + 2] + lds[cc * 256 + b2 * 4 + 3];
    v += comb_b[col];
    comb[(size_t)b2 * HN + col] = fmaxf(v, 0.f);
  }
}

// D6: per-block partial argmax over its 125 adv_W columns for all 64 rows.
__device__ __forceinline__ void d6_values(const float* __restrict__ top,
    const float* __restrict__ adv_W, float* __restrict__ pval, int* __restrict__ pidx,
    int bid, float* lds)
{
  const int tid = threadIdx.x;
  const int c0 = bid * 125;
  float4* tl = (float4*)lds;           // 2048 quads (32KB)
  float* sval = lds + 8192;
  int* sidx = (int*)(lds + 8192 + 256);

  int voff[8], loff[8];
#pragma unroll
  for (int i = 0; i < 8; ++i) {
    int tau = tid + (i << 8);
    int b = tau >> 5, kq = tau & 31;
    voff[i] = b * HN + (kq << 2);
    loff[i] = (b << 5) + (kq ^ (b & 7));
  }
  float4 pv[8];
#pragma unroll
  for (int i = 0; i < 8; ++i) pv[i] = ld4(top + voff[i]);

  const int bl = tid & 63;
  const int half = tid >> 6;
  const int rdbase = bl << 5;
  const int rdx = bl & 7;

  float acc[32];
#pragma unroll
  for (int i = 0; i < 32; ++i) acc[i] = 0.f;

#pragma unroll 1
  for (int ch = 0; ch < 4; ++ch) {
    __syncthreads();
#pragma unroll
    for (int i = 0; i < 8; ++i) tl[loff[i]] = pv[i];
    __syncthreads();
    if (ch < 3) {
#pragma unroll
      for (int i = 0; i < 8; ++i) pv[i] = ld4(top + voff[i] + (ch + 1) * 128);
    }
    const int kk0 = ch << 7;
#pragma unroll
    for (int g = 0; g < 4; ++g) {
      const float* ar[8];
#pragma unroll
      for (int jj = 0; jj < 8; ++jj) {
        int c = c0 + (half << 5) + (g << 3) + jj;
        if (c > VOCN - 1) c = VOCN - 1;
        ar[jj] = adv_W + (size_t)c * HN + kk0;
      }
#pragma unroll 4
      for (int kq = 0; kq < 32; ++kq) {
        float4 tv = tl[rdbase + (kq ^ rdx)];
        const int kk = kq << 2;
        acc[(g << 3) + 0] = dot4(tv, ld4(ar[0] + kk), acc[(g << 3) + 0]);
        acc[(g << 3) + 1] = dot4(tv, ld4(ar[1] + kk), acc[(g << 3) + 1]);
        acc[(g << 3) + 2] = dot4(tv, ld4(ar[2] + kk), acc[(g << 3) + 2]);
        acc[(g << 3) + 3] = dot4(tv, ld4(ar[3] + kk), acc[(g << 3) + 3]);
        acc[(g << 3) + 4] = dot4(tv, ld4(ar[4] + kk), acc[(g << 3) + 4]);
        acc[(g << 3) + 5] = dot4(tv, ld4(ar[5] + kk), acc[(g << 3) + 5]);
        acc[(g << 3) + 6] = dot4(tv, ld4(ar[6] + kk), acc[(g << 3) + 6]);
        acc[(g << 3) + 7] = dot4(tv, ld4(ar[7] + kk), acc[(g << 3) + 7]);
      }
    }
  }
  float bv = -3.4e38f; int bi = 2147483647;
#pragma unroll
  for (int i = 0; i < 32; ++i) {
    const int cl = (half << 5) + i;
    if (cl < 125) {
      float v = acc[i];
      if (v > bv) { bv = v; bi = c0 + cl; }   // ascending order -> first-max on ties
    }
  }
  sval[(bl << 2) + half] = bv;
  sidx[(bl << 2) + half] = bi;
  __syncthreads();
  if (tid < 64) {
    float v = sval[tid << 2]; int ii = sidx[tid << 2];
#pragma unroll
    for (int h2 = 1; h2 < 4; ++h2) {
      float v2 = sval[(tid << 2) + h2]; int i2 = sidx[(tid << 2) + h2];
      if (v2 > v || (v2 == v && i2 < ii)) { v = v2; ii = i2; }
    }
    pval[bid * 64 + tid] = v;
    pidx[bid * 64 + tid] = ii;
  }
}

// D7 (block 0): avg dot + global argmax reduce -> q, next word
__device__ __forceinline__ void d7_reduce(const float* __restrict__ top,
    const float* __restrict__ avg_W, const float* __restrict__ pval,
    const int* __restrict__ pidx, float* __restrict__ qs_out,
    int* __restrict__ word_buf, float* lds)
{
  const int tid = threadIdx.x;
  const int b = tid & 63, q = tid >> 6;
  const float* tr = top + (size_t)b * HN;
  float p = 0.f;
  const int kbeg = q << 7;
  for (int k = kbeg; k < kbeg + 128; k += 4)
    p = dot4(ld4(tr + k), ld4(avg_W + k), p);
  float* av = lds;            // [64][4]
  float* avl = lds + 256;     // [64]
  float* rv = lds + 320;      // [64][4]
  int* ri = (int*)(lds + 576);// [64][4]
  av[(b << 2) + q] = p;
  __syncthreads();
  if (tid < 64)
    avl[tid] = av[tid * 4] + av[tid * 4 + 1] + av[tid * 4 + 2] + av[tid * 4 + 3];
  float bv = -3.4e38f; int bi = 2147483647;
#pragma unroll 4
  for (int pp = (q << 6); pp < (q << 6) + 64; ++pp) {
    float v = pval[pp * 64 + b]; int ii = pidx[pp * 64 + b];
    if (v > bv || (v == bv && ii < bi)) { bv = v; bi = ii; }
  }
  rv[(b << 2) + q] = bv;
  ri[(b << 2) + q] = bi;
  __syncthreads();
  if (tid < 64) {
    float v = rv[tid << 2]; int ii = ri[tid << 2];
#pragma unroll
    for (int k = 1; k < 4; ++k) {
      float v2 = rv[(tid << 2) + k]; int i2 = ri[(tid << 2) + k];
      if (v2 > v || (v2 == v && i2 < ii)) { v = v2; ii = i2; }
    }
    qs_out[tid] = v + avl[tid];
    word_buf[tid] = ii;
  }
}

__global__ void __launch_bounds__(256)
seq2seq_kernel(const int* __restrict__ input, const float* __restrict__ emb_enc,
               const float* __restrict__ emb_dec,
               const float* __restrict__ enc_Wih, const float* __restrict__ enc_Whh,
               const float* __restrict__ enc_bih, const float* __restrict__ enc_bhh,
               const float* __restrict__ dec_Wih, const float* __restrict__ dec_Whh,
               const float* __restrict__ dec_bih, const float* __restrict__ dec_bhh,
               const float* __restrict__ attn_W, const float* __restrict__ attn_b,
               const float* __restrict__ comb_W, const float* __restrict__ comb_b,
               const float* __restrict__ avg_W, const float* __restrict__ adv_W,
               float* __restrict__ out, float* __restrict__ ws)
{
  __shared__ float lds[8704];   // 34KB: max(gru 32KB, d6 32KB+1KB reduce)
  const int bid = blockIdx.x;
  int* wsi = (int*)ws;
  float* hbuf = ws + WS_H;                    // [parity][L][B][H], parity stride 65536
  int* word_buf = (int*)(ws + WS_WORD);
  float* a_buf = ws + WS_A;
  float* applied = ws + WS_APPLIED;
  float* comb = ws + WS_COMB;
  float* pval = ws + WS_PVAL;
  int* pidx = (int*)(ws + WS_PIDX);
  float* gru_out = ws + WS_GRUOUT;
  int gen = 0;

  // ---------------- encoder: software-pipelined, 1 barrier/step ----------------
#pragma unroll 1
  for (int p = 0; p <= 256; ++p) {
    if (bid < 128) {
      if (p < 256) {          // layer 0 of step p:  h0^p -> h0^{p+1}
        const int t = p;
        gru_phase(emb_enc, input + t * BN,
                  hbuf + (size_t)(t & 1) * 65536,               // h0^t
                  enc_Wih, enc_Whh, enc_bih, enc_bhh,
                  hbuf + (size_t)((t + 1) & 1) * 65536,         // h0^{t+1}
                  nullptr, bid, lds);
      }
    } else {
      if (p >= 1) {           // layer 1 of step p-1 (consumes h0^{p} from prev phase)
        const int t = p - 1;
        gru_phase(hbuf + (size_t)((t + 1) & 1) * 65536, nullptr, // x = h0^{t+1}
                  hbuf + (size_t)(t & 1) * 65536 + 32768,        // h1^t
                  enc_Wih + 786432, enc_Whh + 786432,
                  enc_bih + 1536, enc_bhh + 1536,
                  hbuf + (size_t)((t + 1) & 1) * 65536 + 32768,  // h1^{t+1}
                  gru_out + (size_t)t * (BN * HN), bid - 128, lds);
      }
    }
    grid_barrier(wsi, ++gen);
  }

  // ---------------- decoder: 32 steps x 7 phases ----------------
#pragma unroll 1
  for (int s = 0; s < 32; ++s) {
    const float* hflat = hbuf + (size_t)(s & 1) * 65536;
    float* hnew = hbuf + (size_t)((s + 1) & 1) * 65536;

    d1_attn(emb_dec, word_buf, s, hflat, attn_W, attn_b, a_buf, bid, lds);
    grid_barrier(wsi, ++gen);

    d2_applied(a_buf, gru_out, applied, bid, lds);
    grid_barrier(wsi, ++gen);

    d3_comb(emb_dec, word_buf, s, applied, comb_W, comb_b, comb, bid, lds);
    grid_barrier(wsi, ++gen);

    if (bid < 128)
      gru_phase(comb, nullptr, hflat, dec_Wih, dec_Whh, dec_bih, dec_bhh,
                hnew, nullptr, bid, lds);
    grid_barrier(wsi, ++gen);

    if (bid < 128)
      gru_phase(hnew, nullptr, hflat + 32768,
                dec_Wih + 786432, dec_Whh + 786432, dec_bih + 1536, dec_bhh + 1536,
                hnew + 32768, out + (size_t)s * (BN * HN), bid, lds);
    grid_barrier(wsi, ++gen);

    d6_values(hnew + 32768, adv_W, pval, pidx, bid, lds);
    grid_barrier(wsi, ++gen);

    if (bid == 0)
      d7_reduce(hnew + 32768, avg_W, pval, pidx,
                out + (size_t)MAXLENN * BN * HN + s * BN, word_buf, lds);
    grid_barrier(wsi, ++gen);
  }
}

extern "C" void kernel_launch(void* const* d_in, const int* in_sizes, int n_in,
                              void* d_out, int out_size, void* d_ws, size_t ws_size,
                              hipStream_t stream) {
  (void)in_sizes; (void)n_in; (void)out_size; (void)ws_size;
  const int* input      = (const int*)d_in[0];
  const float* emb_enc  = (const float*)d_in[1];
  const float* emb_dec  = (const float*)d_in[2];
  const float* enc_Wih  = (const float*)d_in[3];
  const float* enc_Whh  = (const float*)d_in[4];
  const float* enc_bih  = (const float*)d_in[5];
  const float* enc_bhh  = (const float*)d_in[6];
  const float* dec_Wih  = (const float*)d_in[7];
  const float* dec_Whh  = (const float*)d_in[8];
  const float* dec_bih  = (const float*)d_in[9];
  const float* dec_bhh  = (const float*)d_in[10];
  const float* attn_W   = (const float*)d_in[11];
  const float* attn_b   = (const float*)d_in[12];
  const float* comb_W   = (const float*)d_in[13];
  const float* comb_b   = (const float*)d_in[14];
  const float* avg_W    = (const float*)d_in[15];
  const float* adv_W    = (const float*)d_in[16];
  float* out = (float*)d_out;
  float* ws  = (float*)d_ws;

  hipMemsetAsync(d_ws, 0, WS_ZERO_BYTES, stream);  // barrier flags/rel + zero h0

  // Plain persistent launch: 256 blocks on 256 CUs, 1 block/CU (4 waves, 34KB LDS)
  // -> all blocks co-resident, flag barrier is safe.
  seq2seq_kernel<<<dim3(256), dim3(256), 0, stream>>>(
      input, emb_enc, emb_dec, enc_Wih, enc_Whh, enc_bih, enc_bhh,
      dec_Wih, dec_Whh, dec_bih, dec_bhh, attn_W, attn_b,
      comb_W, comb_b, avg_W, adv_W, out, ws);
}

// Round 4
// 21934.642 us; speedup vs baseline: 1.4170x; 1.2162x over previous
//
#include <hip/hip_runtime.h>
#include <math.h>

#define VOCN 32000
#define HN 512
#define TN 256
#define BN 64
#define MAXLENN 32
#define SOSW 1

// ---------------- workspace layout (float/int32 units) ----------------
#define WS_FLAG     0                       // 256 blocks * 32 ints (128B line each)
#define WS_REL      8192                    // 8 release lines * 16 ints (+pad to 256)
#define WS_H        8448                    // h buffers [2 parity][2 layer][64][512]
#define WS_WORD     (WS_H + 131072)         // 64 ints
#define WS_A        (WS_WORD + 64)          // a[64][256]  (b-major)
#define WS_APPLIED  (WS_A + 16384)          // [64][512]
#define WS_COMB     (WS_APPLIED + 32768)    // [64][512]
#define WS_PVAL     (WS_COMB + 32768)       // [64][256]  (b-major, transposed)
#define WS_PIDX     (WS_PVAL + 16384)       // [64][256] int
#define WS_GRUOUT   (WS_PIDX + 16384)       // [256][64][512]
#define WS_ZERO_BYTES ((WS_H + 131072) * 4) // zero flags + rel + h state

typedef float f4 __attribute__((ext_vector_type(4)));

__device__ __forceinline__ f4 ld4(const float* p) { return *(const f4*)p; }
__device__ __forceinline__ float dot4(f4 a, f4 b, float acc) {
  acc = fmaf(a.x, b.x, acc); acc = fmaf(a.y, b.y, acc);
  acc = fmaf(a.z, b.z, acc); acc = fmaf(a.w, b.w, acc); return acc;
}
__device__ __forceinline__ f4 relu4(f4 v) {
  v.x = fmaxf(v.x, 0.f); v.y = fmaxf(v.y, 0.f);
  v.z = fmaxf(v.z, 0.f); v.w = fmaxf(v.w, 0.f); return v;
}
__device__ __forceinline__ float sigmoidf_(float x) { return 1.f / (1.f + expf(-x)); }

// ---- agent-coherent (L1+L2-bypassing, sc0 sc1) loads/stores. These hit the
// coherence point (L3) directly, so NO cache flush/invalidate fence is needed
// for cross-XCD visibility. Weights keep plain cached loads -> L2-resident.
__device__ __forceinline__ float ldcg(const float* p) {
  float v;
  asm volatile("global_load_dword %0, %1, off sc0 sc1\n\ts_waitcnt vmcnt(0)"
               : "=&v"(v) : "v"(p) : "memory");
  return v;
}
__device__ __forceinline__ int ldcg_i(const int* p) {
  int v;
  asm volatile("global_load_dword %0, %1, off sc0 sc1\n\ts_waitcnt vmcnt(0)"
               : "=&v"(v) : "v"(p) : "memory");
  return v;
}
__device__ __forceinline__ void stcg(float* p, float v) {
  asm volatile("global_store_dword %0, %1, off sc0 sc1" :: "v"(p), "v"(v) : "memory");
}
__device__ __forceinline__ void stcg_i(int* p, int v) {
  asm volatile("global_store_dword %0, %1, off sc0 sc1" :: "v"(p), "v"(v) : "memory");
}
__device__ __forceinline__ void ldcg_b4(const float* p0, const float* p1,
                                        const float* p2, const float* p3,
                                        f4& v0, f4& v1, f4& v2, f4& v3) {
  asm volatile(
      "global_load_dwordx4 %0, %4, off sc0 sc1\n\t"
      "global_load_dwordx4 %1, %5, off sc0 sc1\n\t"
      "global_load_dwordx4 %2, %6, off sc0 sc1\n\t"
      "global_load_dwordx4 %3, %7, off sc0 sc1\n\t"
      "s_waitcnt vmcnt(0)"
      : "=&v"(v0), "=&v"(v1), "=&v"(v2), "=&v"(v3)
      : "v"(p0), "v"(p1), "v"(p2), "v"(p3)
      : "memory");
}
__device__ __forceinline__ void ldcg_b8(const float* p0, const float* p1,
    const float* p2, const float* p3, const float* p4, const float* p5,
    const float* p6, const float* p7,
    f4& v0, f4& v1, f4& v2, f4& v3, f4& v4, f4& v5, f4& v6, f4& v7) {
  asm volatile(
      "global_load_dwordx4 %0, %8, off sc0 sc1\n\t"
      "global_load_dwordx4 %1, %9, off sc0 sc1\n\t"
      "global_load_dwordx4 %2, %10, off sc0 sc1\n\t"
      "global_load_dwordx4 %3, %11, off sc0 sc1\n\t"
      "global_load_dwordx4 %4, %12, off sc0 sc1\n\t"
      "global_load_dwordx4 %5, %13, off sc0 sc1\n\t"
      "global_load_dwordx4 %6, %14, off sc0 sc1\n\t"
      "global_load_dwordx4 %7, %15, off sc0 sc1\n\t"
      "s_waitcnt vmcnt(0)"
      : "=&v"(v0), "=&v"(v1), "=&v"(v2), "=&v"(v3),
        "=&v"(v4), "=&v"(v5), "=&v"(v6), "=&v"(v7)
      : "v"(p0), "v"(p1), "v"(p2), "v"(p3), "v"(p4), "v"(p5), "v"(p6), "v"(p7)
      : "memory");
}
// 8 contiguous quads (128B) from one base pointer
__device__ __forceinline__ void ldcg_row8(const float* p, f4 (&v)[8]) {
  asm volatile(
      "global_load_dwordx4 %0, %8, off sc0 sc1\n\t"
      "global_load_dwordx4 %1, %8, off offset:16 sc0 sc1\n\t"
      "global_load_dwordx4 %2, %8, off offset:32 sc0 sc1\n\t"
      "global_load_dwordx4 %3, %8, off offset:48 sc0 sc1\n\t"
      "global_load_dwordx4 %4, %8, off offset:64 sc0 sc1\n\t"
      "global_load_dwordx4 %5, %8, off offset:80 sc0 sc1\n\t"
      "global_load_dwordx4 %6, %8, off offset:96 sc0 sc1\n\t"
      "global_load_dwordx4 %7, %8, off offset:112 sc0 sc1\n\t"
      "s_waitcnt vmcnt(0)"
      : "=&v"(v[0]), "=&v"(v[1]), "=&v"(v[2]), "=&v"(v[3]),
        "=&v"(v[4]), "=&v"(v[5]), "=&v"(v[6]), "=&v"(v[7])
      : "v"(p)
      : "memory");
}

// Grid barrier with NO cache maintenance: coherent stores are already at the
// coherence point once vmcnt drains; flags/releases are relaxed agent atomics
// (sc0 sc1 dword ops). Monotone generation, pre-zeroed slots.
__device__ __forceinline__ void grid_barrier(int* wsi, int gen) {
  asm volatile("s_waitcnt vmcnt(0) lgkmcnt(0)" ::: "memory");  // every wave drains its stores
  __syncthreads();
  const int bid = blockIdx.x;
  const int tid = threadIdx.x;
  if (bid == 0) {
    if (tid == 0)
      __hip_atomic_store(wsi + WS_FLAG, gen, __ATOMIC_RELAXED, __HIP_MEMORY_SCOPE_AGENT);
    int* fp = wsi + WS_FLAG + tid * 32;
    for (;;) {
      int v = __hip_atomic_load(fp, __ATOMIC_RELAXED, __HIP_MEMORY_SCOPE_AGENT);
      if (__syncthreads_and(v >= gen)) break;
      __builtin_amdgcn_s_sleep(2);
    }
    if (tid < 8)
      __hip_atomic_store(wsi + WS_REL + tid * 16, gen, __ATOMIC_RELAXED, __HIP_MEMORY_SCOPE_AGENT);
    __syncthreads();
  } else {
    if (tid == 0) {
      __hip_atomic_store(wsi + WS_FLAG + bid * 32, gen, __ATOMIC_RELAXED, __HIP_MEMORY_SCOPE_AGENT);
      int* rp = wsi + WS_REL + (bid & 7) * 16;
      while (__hip_atomic_load(rp, __ATOMIC_RELAXED, __HIP_MEMORY_SCOPE_AGENT) < gen)
        __builtin_amdgcn_s_sleep(2);
    }
    __syncthreads();
  }
}

// GRU layer phase. 128 blocks: bg=rb>>6 (batch half), jg=rb&63. Each thread:
// all 3 gates for one (b,j), full K=512. x/h staged in LDS (XOR-swizzled).
// h (and x when x is a communicated buffer) use coherent loads; weights cached.
__device__ __forceinline__ void gru_phase(
    const float* __restrict__ x_base, const int* __restrict__ tok,
    const float* __restrict__ h_rows,
    const float* __restrict__ Wih, const float* __restrict__ Whh,
    const float* __restrict__ bih, const float* __restrict__ bhh,
    float* __restrict__ h_out, float* __restrict__ aux_out,
    int rb, float* lds)
{
  const int tid = threadIdx.x;
  const int bg = rb >> 6;
  const int jg = rb & 63;
  f4* x4l = (f4*)lds;          // 1024 quads (16KB)
  f4* h4l = ((f4*)lds) + 1024; // 1024 quads (16KB)

  const float* xp[4]; const float* hp[4]; int loff[4];
#pragma unroll
  for (int i = 0; i < 4; ++i) {
    int tau = tid + (i << 8);
    int b = tau >> 5;        // [0,32)
    int kq = tau & 31;
    int gb = bg * 32 + b;
    const float* xr = tok ? (x_base + (size_t)tok[gb] * HN) : (x_base + (size_t)gb * HN);
    xp[i] = xr + (kq << 2);
    hp[i] = h_rows + (size_t)gb * HN + (kq << 2);
    loff[i] = (b << 5) + (kq ^ (b & 7));
  }
  const bool cachedx = (tok != nullptr);  // x = embedding table -> cached; also relu flag
  f4 pxv[4], phv[4];
  if (cachedx) {
#pragma unroll
    for (int i = 0; i < 4; ++i) pxv[i] = ld4(xp[i]);
    ldcg_b4(hp[0], hp[1], hp[2], hp[3], phv[0], phv[1], phv[2], phv[3]);
  } else {
    ldcg_b8(xp[0], xp[1], xp[2], xp[3], hp[0], hp[1], hp[2], hp[3],
            pxv[0], pxv[1], pxv[2], pxv[3], phv[0], phv[1], phv[2], phv[3]);
  }

  const int bl = tid & 31;
  const int jl = tid >> 5;          // [0,8)
  const int j = (jg << 3) + jl;     // [0,512)
  const float* wi0 = Wih + (size_t)j * HN;
  const float* wi1 = Wih + (size_t)(512 + j) * HN;
  const float* wi2 = Wih + (size_t)(1024 + j) * HN;
  const float* wh0 = Whh + (size_t)j * HN;
  const float* wh1 = Whh + (size_t)(512 + j) * HN;
  const float* wh2 = Whh + (size_t)(1024 + j) * HN;
  float ax0 = 0.f, ax1 = 0.f, ax2 = 0.f, ah0 = 0.f, ah1 = 0.f, ah2 = 0.f;
  const int rdbase = bl << 5;
  const int rdx = bl & 7;

#pragma unroll 1
  for (int ch = 0; ch < 4; ++ch) {
    __syncthreads();
#pragma unroll
    for (int i = 0; i < 4; ++i) {
      x4l[loff[i]] = cachedx ? relu4(pxv[i]) : pxv[i];
      h4l[loff[i]] = phv[i];
    }
    __syncthreads();
    if (ch < 3) {
      const int off = (ch + 1) * 128;
      if (cachedx) {
#pragma unroll
        for (int i = 0; i < 4; ++i) pxv[i] = ld4(xp[i] + off);
        ldcg_b4(hp[0] + off, hp[1] + off, hp[2] + off, hp[3] + off,
                phv[0], phv[1], phv[2], phv[3]);
      } else {
        ldcg_b8(xp[0] + off, xp[1] + off, xp[2] + off, xp[3] + off,
                hp[0] + off, hp[1] + off, hp[2] + off, hp[3] + off,
                pxv[0], pxv[1], pxv[2], pxv[3], phv[0], phv[1], phv[2], phv[3]);
      }
    }
    const int k0 = ch << 7;
#pragma unroll 4
    for (int kq = 0; kq < 32; ++kq) {
      f4 xv = x4l[rdbase + (kq ^ rdx)];
      f4 hv = h4l[rdbase + (kq ^ rdx)];
      const int kk = k0 + (kq << 2);
      ax0 = dot4(xv, ld4(wi0 + kk), ax0);
      ah0 = dot4(hv, ld4(wh0 + kk), ah0);
      ax1 = dot4(xv, ld4(wi1 + kk), ax1);
      ah1 = dot4(hv, ld4(wh1 + kk), ah1);
      ax2 = dot4(xv, ld4(wi2 + kk), ax2);
      ah2 = dot4(hv, ld4(wh2 + kk), ah2);
    }
  }
  const int gb = bg * 32 + bl;
  const float hold = ldcg(h_rows + (size_t)gb * HN + j);
  const float r = sigmoidf_(ax0 + bih[j] + ah0 + bhh[j]);
  const float z = sigmoidf_(ax1 + bih[512 + j] + ah1 + bhh[512 + j]);
  const float n = tanhf(ax2 + bih[1024 + j] + r * (ah2 + bhh[1024 + j]));
  const float hv = (1.f - z) * n + z * hold;
  stcg(h_out + (size_t)gb * HN + j, hv);
  if (aux_out) stcg(aux_out + (size_t)gb * HN + j, hv);
}

// D1: a[b, tau=bid] = relu(cat(e, sv) @ attn_W[tau] + attn_b[tau]); sv raw reshape.
__device__ __forceinline__ void d1_attn(
    const float* __restrict__ emb_dec, const int* __restrict__ word_buf, int s,
    const float* __restrict__ hflat, const float* __restrict__ attn_W,
    const float* __restrict__ attn_b, float* __restrict__ a_buf, int bid, float* lds)
{
  const int tid = threadIdx.x;
  const int b = tid & 63, q = tid >> 6;
  const int wb = (s == 0) ? SOSW : ldcg_i(word_buf + b);
  const float* er = emb_dec + (size_t)wb * HN;
  const float* hr = hflat + b * 1024;
  const float* wr = attn_W + (size_t)bid * 1536;
  float acc = 0.f;
  const int kbeg = q * 384, kend = kbeg + 384;
  int k = kbeg;
  const int kc = (kend < 512) ? kend : 512;
  for (; k < kc; k += 4)
    acc = dot4(relu4(ld4(er + k)), ld4(wr + k), acc);
  if (k < 512) k = 512;
  for (; k < kend; k += 32) {
    f4 hv[8]; ldcg_row8(hr + (k - 512), hv);
#pragma unroll
    for (int jq = 0; jq < 8; ++jq)
      acc = dot4(hv[jq], ld4(wr + k + (jq << 2)), acc);
  }
  lds[(b << 2) + q] = acc;
  __syncthreads();
  if (tid < 64) {
    float v = lds[tid * 4] + lds[tid * 4 + 1] + lds[tid * 4 + 2] + lds[tid * 4 + 3];
    v += attn_b[bid];
    stcg(a_buf + tid * 256 + bid, fmaxf(v, 0.f));
  }
}

// D2: applied[b,h] = sum_t a[b,t]*gru_out[t,b,h]; block=(b, h-chunk of 128).
// a staged into LDS coherently once; gru_out plain-cached (read-only, post-fence).
__device__ __forceinline__ void d2_applied(const float* __restrict__ a_buf,
    const float* __restrict__ gru_out, float* __restrict__ applied, int bid, float* lds)
{
  const int tid = threadIdx.x;
  const int b = bid & 63, hc = bid >> 6;
  f4* al4 = (f4*)lds;          // 64 quads = a[b][0..256)
  float* al = lds;
  float* red = lds + 256;
  if (tid < 64) {
    f4 av;
    const float* p = a_buf + b * 256 + (tid << 2);
    asm volatile("global_load_dwordx4 %0, %1, off sc0 sc1\n\ts_waitcnt vmcnt(0)"
                 : "=&v"(av) : "v"(p) : "memory");
    al4[tid] = av;
  }
  __syncthreads();
  const int hl = tid & 127, th = tid >> 7;
  const int hh = (hc << 7) + hl;
  const float* gp = gru_out + (size_t)b * HN + hh;
  float acc = 0.f;
  const int t0 = th << 7;
#pragma unroll 4
  for (int t = t0; t < t0 + 128; ++t)
    acc = fmaf(al[t], gp[(size_t)t * (BN * HN)], acc);
  red[tid] = acc;
  __syncthreads();
  if (tid < 128)
    stcg(applied + (size_t)b * HN + (hc << 7) + tid, red[tid] + red[tid + 128]);
}

// D3: comb[b,col] = relu(cat(e, applied) @ comb_W[col] + comb_b[col]); 2 cols/block
__device__ __forceinline__ void d3_comb(const float* __restrict__ emb_dec,
    const int* __restrict__ word_buf, int s, const float* __restrict__ applied,
    const float* __restrict__ comb_W, const float* __restrict__ comb_b,
    float* __restrict__ comb, int bid, float* lds)
{
  const int tid = threadIdx.x;
  const int b = tid & 63, q = tid >> 6;
  const int wb = (s == 0) ? SOSW : ldcg_i(word_buf + b);
  const float* er = emb_dec + (size_t)wb * HN;
  const float* apr = applied + (size_t)b * HN;
#pragma unroll
  for (int cc = 0; cc < 2; ++cc) {
    const int col = (bid << 1) + cc;
    const float* wr = comb_W + (size_t)col * 1024;
    float acc = 0.f;
    const int kbeg = q << 8, kend = kbeg + 256;
    int k = kbeg;
    const int kc = (kend < 512) ? kend : 512;
    for (; k < kc; k += 4)
      acc = dot4(relu4(ld4(er + k)), ld4(wr + k), acc);
    if (k < 512) k = 512;
    for (; k < kend; k += 32) {
      f4 av[8]; ldcg_row8(apr + (k - 512), av);
#pragma unroll
      for (int jq = 0; jq < 8; ++jq)
        acc = dot4(av[jq], ld4(wr + k + (jq << 2)), acc);
    }
    lds[cc * 256 + (b << 2) + q] = acc;
  }
  __syncthreads();
  if (tid < 128) {
    const int cc = tid >> 6, b2 = tid & 63;
    const int col = (bid << 1) + cc;
    float v = lds[cc * 256 + b2 * 4] + lds[cc * 256 + b2 * 4 + 1] +
              lds[cc * 256 + b2 * 4 + 2] + lds[cc * 256 + b2 * 4 + 3];
    v += comb_b[col];
    stcg(comb + (size_t)b2 * HN + col, fmaxf(v, 0.f));
  }
}

// D6: per-block partial argmax over its 125 adv_W columns, all 64 rows.
// top read coherently; adv_W plain cached; pval/pidx written b-major (transposed).
__device__ __forceinline__ void d6_values(const float* __restrict__ top,
    const float* __restrict__ adv_W, float* __restrict__ pval, int* __restrict__ pidx,
    int bid, float* lds)
{
  const int tid = threadIdx.x;
  const int c0 = bid * 125;
  f4* tl = (f4*)lds;           // 2048 quads (32KB)
  float* sval = lds + 8192;
  int* sidx = (int*)(lds + 8192 + 256);

  const float* tp[8]; int loff[8];
#pragma unroll
  for (int i = 0; i < 8; ++i) {
    int tau = tid + (i << 8);
    int b = tau >> 5, kq = tau & 31;
    tp[i] = top + b * HN + (kq << 2);
    loff[i] = (b << 5) + (kq ^ (b & 7));
  }
  f4 pv[8];
  ldcg_b8(tp[0], tp[1], tp[2], tp[3], tp[4], tp[5], tp[6], tp[7],
          pv[0], pv[1], pv[2], pv[3], pv[4], pv[5], pv[6], pv[7]);

  const int bl = tid & 63;
  const int half = tid >> 6;
  const int rdbase = bl << 5;
  const int rdx = bl & 7;

  float acc[32];
#pragma unroll
  for (int i = 0; i < 32; ++i) acc[i] = 0.f;

#pragma unroll 1
  for (int ch = 0; ch < 4; ++ch) {
    __syncthreads();
#pragma unroll
    for (int i = 0; i < 8; ++i) tl[loff[i]] = pv[i];
    __syncthreads();
    if (ch < 3) {
      const int off = (ch + 1) * 128;
      ldcg_b8(tp[0] + off, tp[1] + off, tp[2] + off, tp[3] + off,
              tp[4] + off, tp[5] + off, tp[6] + off, tp[7] + off,
              pv[0], pv[1], pv[2], pv[3], pv[4], pv[5], pv[6], pv[7]);
    }
    const int kk0 = ch << 7;
#pragma unroll
    for (int g = 0; g < 4; ++g) {
      const float* ar[8];
#pragma unroll
      for (int jj = 0; jj < 8; ++jj) {
        int c = c0 + (half << 5) + (g << 3) + jj;
        if (c > VOCN - 1) c = VOCN - 1;
        ar[jj] = adv_W + (size_t)c * HN + kk0;
      }
#pragma unroll 4
      for (int kq = 0; kq < 32; ++kq) {
        f4 tv = tl[rdbase + (kq ^ rdx)];
        const int kk = kq << 2;
        acc[(g << 3) + 0] = dot4(tv, ld4(ar[0] + kk), acc[(g << 3) + 0]);
        acc[(g << 3) + 1] = dot4(tv, ld4(ar[1] + kk), acc[(g << 3) + 1]);
        acc[(g << 3) + 2] = dot4(tv, ld4(ar[2] + kk), acc[(g << 3) + 2]);
        acc[(g << 3) + 3] = dot4(tv, ld4(ar[3] + kk), acc[(g << 3) + 3]);
        acc[(g << 3) + 4] = dot4(tv, ld4(ar[4] + kk), acc[(g << 3) + 4]);
        acc[(g << 3) + 5] = dot4(tv, ld4(ar[5] + kk), acc[(g << 3) + 5]);
        acc[(g << 3) + 6] = dot4(tv, ld4(ar[6] + kk), acc[(g << 3) + 6]);
        acc[(g << 3) + 7] = dot4(tv, ld4(ar[7] + kk), acc[(g << 3) + 7]);
      }
    }
  }
  float bv = -3.4e38f; int bi = 2147483647;
#pragma unroll
  for (int i = 0; i < 32; ++i) {
    const int cl = (half << 5) + i;
    if (cl < 125) {
      float v = acc[i];
      if (v > bv) { bv = v; bi = c0 + cl; }   // ascending order -> first-max on ties
    }
  }
  sval[(bl << 2) + half] = bv;
  sidx[(bl << 2) + half] = bi;
  __syncthreads();
  if (tid < 64) {
    float v = sval[tid << 2]; int ii = sidx[tid << 2];
#pragma unroll
    for (int h2 = 1; h2 < 4; ++h2) {
      float v2 = sval[(tid << 2) + h2]; int i2 = sidx[(tid << 2) + h2];
      if (v2 > v || (v2 == v && i2 < ii)) { v = v2; ii = i2; }
    }
    stcg(pval + tid * 256 + bid, v);      // [b][block]
    stcg_i(pidx + tid * 256 + bid, ii);
  }
}

// D7 (block 0): avg dot + global argmax reduce -> q, next word
__device__ __forceinline__ void d7_reduce(const float* __restrict__ top,
    const float* __restrict__ avg_W, const float* __restrict__ pval,
    const int* __restrict__ pidx, float* __restrict__ qs_out,
    int* __restrict__ word_buf, float* lds)
{
  const int tid = threadIdx.x;
  const int b = tid & 63, q = tid >> 6;
  const float* tr = top + (size_t)b * HN;
  float p = 0.f;
  const int kbeg = q << 7;
#pragma unroll
  for (int bb = 0; bb < 4; ++bb) {
    f4 tv[8]; ldcg_row8(tr + kbeg + bb * 32, tv);
#pragma unroll
    for (int jq = 0; jq < 8; ++jq)
      p = dot4(tv[jq], ld4(avg_W + kbeg + bb * 32 + (jq << 2)), p);
  }
  float* av = lds;            // [64][4]
  float* avl = lds + 256;     // [64]
  float* rv = lds + 320;      // [64][4]
  int* ri = (int*)(lds + 576);// [64][4]
  av[(b << 2) + q] = p;
  __syncthreads();
  if (tid < 64)
    avl[tid] = av[tid * 4] + av[tid * 4 + 1] + av[tid * 4 + 2] + av[tid * 4 + 3];
  float bv = -3.4e38f; int bi = 2147483647;
  const float* pvr = pval + b * 256 + (q << 6);
  const float* pir = (const float*)(pidx) + b * 256 + (q << 6);
#pragma unroll
  for (int bb = 0; bb < 2; ++bb) {
    f4 v4[8], i4[8];
    ldcg_row8(pvr + bb * 32, v4);
    ldcg_row8(pir + bb * 32, i4);
#pragma unroll
    for (int jq = 0; jq < 8; ++jq) {
      float vv[4] = { v4[jq].x, v4[jq].y, v4[jq].z, v4[jq].w };
      int iv[4] = { __float_as_int(i4[jq].x), __float_as_int(i4[jq].y),
                    __float_as_int(i4[jq].z), __float_as_int(i4[jq].w) };
#pragma unroll
      for (int c = 0; c < 4; ++c) {
        if (vv[c] > bv || (vv[c] == bv && iv[c] < bi)) { bv = vv[c]; bi = iv[c]; }
      }
    }
  }
  rv[(b << 2) + q] = bv;
  ri[(b << 2) + q] = bi;
  __syncthreads();
  if (tid < 64) {
    float v = rv[tid << 2]; int ii = ri[tid << 2];
#pragma unroll
    for (int k = 1; k < 4; ++k) {
      float v2 = rv[(tid << 2) + k]; int i2 = ri[(tid << 2) + k];
      if (v2 > v || (v2 == v && i2 < ii)) { v = v2; ii = i2; }
    }
    qs_out[tid] = v + avl[tid];
    stcg_i(word_buf + tid, ii);
  }
}

__global__ void __launch_bounds__(256)
seq2seq_kernel(const int* __restrict__ input, const float* __restrict__ emb_enc,
               const float* __restrict__ emb_dec,
               const float* __restrict__ enc_Wih, const float* __restrict__ enc_Whh,
               const float* __restrict__ enc_bih, const float* __restrict__ enc_bhh,
               const float* __restrict__ dec_Wih, const float* __restrict__ dec_Whh,
               const float* __restrict__ dec_bih, const float* __restrict__ dec_bhh,
               const float* __restrict__ attn_W, const float* __restrict__ attn_b,
               const float* __restrict__ comb_W, const float* __restrict__ comb_b,
               const float* __restrict__ avg_W, const float* __restrict__ adv_W,
               float* __restrict__ out, float* __restrict__ ws)
{
  __shared__ float lds[8704];   // 34KB: max(gru 32KB, d6 32KB+1KB reduce)
  const int bid = blockIdx.x;
  int* wsi = (int*)ws;
  float* hbuf = ws + WS_H;                    // [parity][L][B][H], parity stride 65536
  int* word_buf = (int*)(ws + WS_WORD);
  float* a_buf = ws + WS_A;
  float* applied = ws + WS_APPLIED;
  float* comb = ws + WS_COMB;
  float* pval = ws + WS_PVAL;
  int* pidx = (int*)(ws + WS_PIDX);
  float* gru_out = ws + WS_GRUOUT;
  int gen = 0;

  // ---------------- encoder: software-pipelined, 1 barrier/step ----------------
#pragma unroll 1
  for (int p = 0; p <= 256; ++p) {
    if (bid < 128) {
      if (p < 256) {          // layer 0 of step p:  h0^p -> h0^{p+1}
        const int t = p;
        gru_phase(emb_enc, input + t * BN,
                  hbuf + (size_t)(t & 1) * 65536,               // h0^t
                  enc_Wih, enc_Whh, enc_bih, enc_bhh,
                  hbuf + (size_t)((t + 1) & 1) * 65536,         // h0^{t+1}
                  nullptr, bid, lds);
      }
    } else {
      if (p >= 1) {           // layer 1 of step p-1 (consumes h0^{p} from prev phase)
        const int t = p - 1;
        gru_phase(hbuf + (size_t)((t + 1) & 1) * 65536, nullptr, // x = h0^{t+1}
                  hbuf + (size_t)(t & 1) * 65536 + 32768,        // h1^t
                  enc_Wih + 786432, enc_Whh + 786432,
                  enc_bih + 1536, enc_bhh + 1536,
                  hbuf + (size_t)((t + 1) & 1) * 65536 + 32768,  // h1^{t+1}
                  gru_out + (size_t)t * (BN * HN), bid - 128, lds);
      }
    }
    grid_barrier(wsi, ++gen);
  }

  // One-time L2 invalidate so d2's PLAIN cached reads of the (now read-only)
  // gru_out can't hit stale poison lines. This is the only cache-flush fence.
  __threadfence();

  // ---------------- decoder: 32 steps x 7 phases ----------------
#pragma unroll 1
  for (int s = 0; s < 32; ++s) {
    const float* hflat = hbuf + (size_t)(s & 1) * 65536;
    float* hnew = hbuf + (size_t)((s + 1) & 1) * 65536;

    d1_attn(emb_dec, word_buf, s, hflat, attn_W, attn_b, a_buf, bid, lds);
    grid_barrier(wsi, ++gen);

    d2_applied(a_buf, gru_out, applied, bid, lds);
    grid_barrier(wsi, ++gen);

    d3_comb(emb_dec, word_buf, s, applied, comb_W, comb_b, comb, bid, lds);
    grid_barrier(wsi, ++gen);

    if (bid < 128)
      gru_phase(comb, nullptr, hflat, dec_Wih, dec_Whh, dec_bih, dec_bhh,
                hnew, nullptr, bid, lds);
    grid_barrier(wsi, ++gen);

    if (bid < 128)
      gru_phase(hnew, nullptr, hflat + 32768,
                dec_Wih + 786432, dec_Whh + 786432, dec_bih + 1536, dec_bhh + 1536,
                hnew + 32768, out + (size_t)s * (BN * HN), bid, lds);
    grid_barrier(wsi, ++gen);

    d6_values(hnew + 32768, adv_W, pval, pidx, bid, lds);
    grid_barrier(wsi, ++gen);

    if (bid == 0)
      d7_reduce(hnew + 32768, avg_W, pval, pidx,
                out + (size_t)MAXLENN * BN * HN + s * BN, word_buf, lds);
    grid_barrier(wsi, ++gen);
  }
}

extern "C" void kernel_launch(void* const* d_in, const int* in_sizes, int n_in,
                              void* d_out, int out_size, void* d_ws, size_t ws_size,
                              hipStream_t stream) {
  (void)in_sizes; (void)n_in; (void)out_size; (void)ws_size;
  const int* input      = (const int*)d_in[0];
  const float* emb_enc  = (const float*)d_in[1];
  const float* emb_dec  = (const float*)d_in[2];
  const float* enc_Wih  = (const float*)d_in[3];
  const float* enc_Whh  = (const float*)d_in[4];
  const float* enc_bih  = (const float*)d_in[5];
  const float* enc_bhh  = (const float*)d_in[6];
  const float* dec_Wih  = (const float*)d_in[7];
  const float* dec_Whh  = (const float*)d_in[8];
  const float* dec_bih  = (const float*)d_in[9];
  const float* dec_bhh  = (const float*)d_in[10];
  const float* attn_W   = (const float*)d_in[11];
  const float* attn_b   = (const float*)d_in[12];
  const float* comb_W   = (const float*)d_in[13];
  const float* comb_b   = (const float*)d_in[14];
  const float* avg_W    = (const float*)d_in[15];
  const float* adv_W    = (const float*)d_in[16];
  float* out = (float*)d_out;
  float* ws  = (float*)d_ws;

  hipMemsetAsync(d_ws, 0, WS_ZERO_BYTES, stream);  // barrier flags/rel + zero h0

  // Plain persistent launch: 256 blocks on 256 CUs, 1 block/CU (4 waves, 34KB LDS)
  // -> all blocks co-resident, flag barrier is safe.
  seq2seq_kernel<<<dim3(256), dim3(256), 0, stream>>>(
      input, emb_enc, emb_dec, enc_Wih, enc_Whh, enc_bih, enc_bhh,
      dec_Wih, dec_Whh, dec_bih, dec_bhh, attn_W, attn_b,
      comb_W, comb_b, avg_W, adv_W, out, ws);
}